// Round 1
// baseline (1116.948 us; speedup 1.0000x reference)
//
#include <hip/hip_runtime.h>

typedef unsigned short u16;
typedef __attribute__((ext_vector_type(8))) short bf16x8;
typedef __attribute__((ext_vector_type(4))) float f32x4;

struct __align__(8) u16x4_t { u16 x, y, z, w; };

__device__ __forceinline__ float b2f(u16 b) {
  union { unsigned u; float f; } v; v.u = ((unsigned)b) << 16; return v.f;
}
__device__ __forceinline__ u16 f2b(float f) {
  union { float f; unsigned u; } v; v.f = f;
  unsigned r = v.u + 0x7fffu + ((v.u >> 16) & 1u);
  return (u16)(r >> 16);
}

// ---------------- mask scatter ----------------
__global__ void set_mask_kernel(const int* __restrict__ main_idx, int* __restrict__ mask, int n) {
  int t = blockIdx.x * 256 + threadIdx.x;
  if (t < n) mask[main_idx[t]] = 1;
}

// ---------------- fp32 -> bf16 convert (vectorized) ----------------
__global__ void cvt_f32_bf16(const float* __restrict__ src, u16* __restrict__ dst, int n4) {
  int t = blockIdx.x * 256 + threadIdx.x;
  if (t >= n4) return;
  float4 v = ((const float4*)src)[t];
  u16x4_t o;
  o.x = f2b(v.x); o.y = f2b(v.y); o.z = f2b(v.z); o.w = f2b(v.w);
  ((u16x4_t*)dst)[t] = o;
}

// ---------------- bf16 MFMA GEMM: C[M,N] = A[M,K] @ B[N,K]^T + bias, opt relu ----------------
// 128x128 tile, BK=64, global_load_lds width=16, 4 waves each computing 64x64.
template<int RELU>
__global__ __launch_bounds__(256, 2)
void gemm_bt_bf16(const u16* __restrict__ A, const u16* __restrict__ B,
                  const float* __restrict__ bias, u16* __restrict__ C,
                  int M, int N, int K) {
  __shared__ u16 lA[128 * 64];
  __shared__ u16 lB[128 * 64];
  const int tid  = threadIdx.x;
  const int lane = tid & 63;
  const int wave = tid >> 6;
  const int m0 = blockIdx.x * 128;
  const int n0 = blockIdx.y * 128;

  f32x4 acc[4][4] = {};

  const int mR = (wave & 1) * 64;
  const int nC = (wave >> 1) * 64;

  for (int kt = 0; kt < K; kt += 64) {
    __syncthreads();  // protect LDS from previous iteration's readers
#pragma unroll
    for (int s = 0; s < 4; ++s) {
      int slot = s * 256 + tid;
      int row  = slot >> 3;          // 8 x 16B segments per 64-elem row
      int kk   = (slot & 7) * 8;
      int ar = m0 + row; ar = (ar < M) ? ar : (M - 1);   // clamp tail rows
      const u16* gA = A + (size_t)ar * K + (kt + kk);
      __builtin_amdgcn_global_load_lds(
          (const __attribute__((address_space(1))) void*)gA,
          (__attribute__((address_space(3))) void*)(lA + s * 2048 + wave * 512),
          16, 0, 0);
      const u16* gB = B + (size_t)(n0 + row) * K + (kt + kk);  // N always %128
      __builtin_amdgcn_global_load_lds(
          (const __attribute__((address_space(1))) void*)gB,
          (__attribute__((address_space(3))) void*)(lB + s * 2048 + wave * 512),
          16, 0, 0);
    }
    __syncthreads();  // drains vmcnt before LDS reads

#pragma unroll
    for (int ks = 0; ks < 2; ++ks) {
      const int kb = ks * 32 + (lane >> 4) * 8;
      bf16x8 af[4], bfr[4];
#pragma unroll
      for (int i = 0; i < 4; ++i) {
        af[i]  = *(const bf16x8*)(lA + (mR + i * 16 + (lane & 15)) * 64 + kb);
        bfr[i] = *(const bf16x8*)(lB + (nC + i * 16 + (lane & 15)) * 64 + kb);
      }
#pragma unroll
      for (int i = 0; i < 4; ++i)
#pragma unroll
        for (int j = 0; j < 4; ++j)
          acc[i][j] = __builtin_amdgcn_mfma_f32_16x16x32_bf16(af[i], bfr[j], acc[i][j], 0, 0, 0);
    }
  }

  // epilogue: C/D layout col=lane&15, row=(lane>>4)*4+reg  (verified m89/m91)
  const int crow = (lane >> 4) * 4;
  const int ccol = lane & 15;
#pragma unroll
  for (int i = 0; i < 4; ++i) {
#pragma unroll
    for (int j = 0; j < 4; ++j) {
      int col = n0 + nC + j * 16 + ccol;
      float bv = bias[col];
#pragma unroll
      for (int q = 0; q < 4; ++q) {
        int row = m0 + mR + i * 16 + crow + q;
        if (row < M) {
          float v = acc[i][j][q] + bv;
          if (RELU) v = fmaxf(v, 0.f);
          C[(size_t)row * N + col] = f2b(v);
        }
      }
    }
  }
}

// ---------------- masked scatter-add: one wave per edge ----------------
__global__ __launch_bounds__(256)
void scatter_edges(const u16* __restrict__ P, const int* __restrict__ obj_idx,
                   const int* __restrict__ evt_idx, const int* __restrict__ mask,
                   float* __restrict__ sums, float* __restrict__ cnt, int nEdge) {
  const int lane = threadIdx.x & 63;
  const int wave = threadIdx.x >> 6;
  const int e = blockIdx.x * 4 + wave;
  if (e >= nEdge) return;
  const int o = obj_idx[e];
  if (!mask[o]) return;   // wave-uniform branch
  const int ev = evt_idx[e];
  u16x4_t pv = *(const u16x4_t*)(P + (size_t)ev * 256 + lane * 4);
  float* srow = sums + (size_t)o * 256 + lane * 4;
  atomicAdd(srow + 0, b2f(pv.x));
  atomicAdd(srow + 1, b2f(pv.y));
  atomicAdd(srow + 2, b2f(pv.z));
  atomicAdd(srow + 3, b2f(pv.w));
  if (lane == 0) atomicAdd(cnt + o, 1.0f);
}

// ---------------- profile = sums / max(cnt,1), store bf16 ----------------
__global__ void profile_div(const float* __restrict__ sums, const float* __restrict__ cnt,
                            u16* __restrict__ prof, int total4) {
  int t = blockIdx.x * 256 + threadIdx.x;
  if (t >= total4) return;
  int row = t >> 6;  // 64 float4 per 256-wide row
  float s = 1.0f / fmaxf(cnt[row], 1.0f);
  float4 v = ((const float4*)sums)[t];
  u16x4_t o;
  o.x = f2b(v.x * s); o.y = f2b(v.y * s); o.z = f2b(v.z * s); o.w = f2b(v.w * s);
  ((u16x4_t*)prof)[t] = o;
}

// ---------------- GRU gates + masked blend ----------------
__global__ __launch_bounds__(256)
void gate_out(const u16* __restrict__ gi, const u16* __restrict__ gh,
              const float* __restrict__ objX, const int* __restrict__ mask,
              float* __restrict__ out, int nObj) {
  const int row = blockIdx.x;
  const int d = threadIdx.x;
  const size_t o256 = (size_t)row * 256 + d;
  float x = objX[o256];
  float res = x;
  if (mask[row]) {
    const size_t o768 = (size_t)row * 768 + d;
    float ir = b2f(gi[o768]), iz = b2f(gi[o768 + 256]), inn = b2f(gi[o768 + 512]);
    float hr = b2f(gh[o768]), hz = b2f(gh[o768 + 256]), hn = b2f(gh[o768 + 512]);
    float r = 1.f / (1.f + __expf(-(ir + hr)));
    float z = 1.f / (1.f + __expf(-(iz + hz)));
    float a = inn + r * hn;
    float n = 1.f - 2.f / (__expf(2.f * a) + 1.f);  // tanh via exp
    res = (1.f - z) * n + z * x;
  }
  out[o256] = res;
}

// ---------------- workspace layout (bytes) ----------------
// [0        , 51.2M)  evtb (bf16 event_X)      -> later reused by gi
// [51.2M    ,102.4M)  P    (bf16 proj events)  -> later reused by gi/gh
// [102.4M   ,153.6M)  sums (fp32)              -> later reused by gh
// [153.6M   ,179.2M)  objb (bf16 object_X)
// [179.2M   ,204.8M)  prof (bf16 profile)
// [204.8M...]         wpb / wib / whb / cnt / mask
// gi = [0, 76.8M)  (valid: evtb+P dead by gemm2a)
// gh = [76.8M, 153.6M) (valid: P+sums dead by gemm2b)
// total required: 206,117,504 bytes

extern "C" void kernel_launch(void* const* d_in, const int* in_sizes, int n_in,
                              void* d_out, int out_size, void* d_ws, size_t ws_size,
                              hipStream_t stream) {
  const float* objX   = (const float*)d_in[0];
  const float* evtX   = (const float*)d_in[1];
  const int* obj_idx  = (const int*)d_in[2];
  const int* evt_idx  = (const int*)d_in[3];
  const int* main_idx = (const int*)d_in[4];
  const float* Wp = (const float*)d_in[5];
  const float* bp = (const float*)d_in[6];
  const float* Wi = (const float*)d_in[7];
  const float* bi = (const float*)d_in[8];
  const float* Wh = (const float*)d_in[9];
  const float* bh = (const float*)d_in[10];

  const int nObj  = in_sizes[0] / 256;   // 50000
  const int nEvt  = in_sizes[1] / 256;   // 100000
  const int nEdge = in_sizes[2];         // 500000
  const int nMain = in_sizes[4];         // 25000

  char* ws = (char*)d_ws;
  u16*   evtb = (u16*)(ws + 0);
  u16*   P    = (u16*)(ws + 51200000);
  float* sums = (float*)(ws + 102400000);
  u16*   objb = (u16*)(ws + 153600000);
  u16*   prof = (u16*)(ws + 179200000);
  u16*   wpb  = (u16*)(ws + 204800000);
  u16*   wib  = (u16*)(ws + 204931072);
  u16*   whb  = (u16*)(ws + 205324288);
  float* cnt  = (float*)(ws + 205717504);
  int*   mask = (int*)(ws + 205917504);
  u16*   gi   = (u16*)(ws + 0);
  u16*   gh   = (u16*)(ws + 76800000);
  float* out  = (float*)d_out;

  // zero sums + cnt + mask (cnt & mask contiguous)
  hipMemsetAsync(sums, 0, 51200000, stream);
  hipMemsetAsync(cnt, 0, 400000, stream);

  set_mask_kernel<<<(nMain + 255) / 256, 256, 0, stream>>>(main_idx, mask, nMain);

  cvt_f32_bf16<<<(in_sizes[1] / 4 + 255) / 256, 256, 0, stream>>>(evtX, evtb, in_sizes[1] / 4);
  cvt_f32_bf16<<<(in_sizes[0] / 4 + 255) / 256, 256, 0, stream>>>(objX, objb, in_sizes[0] / 4);
  cvt_f32_bf16<<<(65536 / 4 + 255) / 256, 256, 0, stream>>>(Wp, wpb, 65536 / 4);
  cvt_f32_bf16<<<(196608 / 4 + 255) / 256, 256, 0, stream>>>(Wi, wib, 196608 / 4);
  cvt_f32_bf16<<<(196608 / 4 + 255) / 256, 256, 0, stream>>>(Wh, whb, 196608 / 4);

  // P = relu(event_bf16 @ Wp^T + bp)   [100000 x 256]
  gemm_bt_bf16<1><<<dim3((nEvt + 127) / 128, 256 / 128), 256, 0, stream>>>(
      evtb, wpb, bp, P, nEvt, 256, 256);

  // masked scatter-mean accumulation
  scatter_edges<<<(nEdge + 3) / 4, 256, 0, stream>>>(P, obj_idx, evt_idx, mask, sums, cnt, nEdge);
  profile_div<<<(nObj * 64 + 255) / 256, 256, 0, stream>>>(sums, cnt, prof, nObj * 64);

  // gi = prof @ Wi^T + bi ; gh = obj @ Wh^T + bh   [50000 x 768]
  gemm_bt_bf16<0><<<dim3((nObj + 127) / 128, 768 / 128), 256, 0, stream>>>(
      prof, wib, bi, gi, nObj, 768, 256);
  gemm_bt_bf16<0><<<dim3((nObj + 127) / 128, 768 / 128), 256, 0, stream>>>(
      objb, whb, bh, gh, nObj, 768, 256);

  // gates + masked blend
  gate_out<<<nObj, 256, 0, stream>>>(gi, gh, objX, mask, out, nObj);
}

// Round 2
// 418.683 us; speedup vs baseline: 2.6678x; 2.6678x over previous
//
#include <hip/hip_runtime.h>

typedef unsigned short u16;
typedef __attribute__((ext_vector_type(8))) short bf16x8;
typedef __attribute__((ext_vector_type(4))) float f32x4;

struct __align__(8) u16x4_t { u16 x, y, z, w; };

__device__ __forceinline__ float b2f(u16 b) {
  union { unsigned u; float f; } v; v.u = ((unsigned)b) << 16; return v.f;
}
__device__ __forceinline__ u16 f2b(float f) {
  union { float f; unsigned u; } v; v.f = f;
  unsigned r = v.u + 0x7fffu + ((v.u >> 16) & 1u);
  return (u16)(r >> 16);
}

// ---------------- mask + unique main list ----------------
__global__ void set_mask_append(const int* __restrict__ main_idx, int* __restrict__ mask,
                                int* __restrict__ mlist, int* __restrict__ cpos,
                                int* __restrict__ mcount, int n) {
  int t = blockIdx.x * 256 + threadIdx.x;
  if (t >= n) return;
  int o = main_idx[t];
  if (atomicCAS(&mask[o], 0, 1) == 0) {
    int i = atomicAdd(mcount, 1);
    mlist[i] = o;
    cpos[o] = i;
  }
}

__global__ void build_rrows(const int* __restrict__ mlist, const int* __restrict__ mcount,
                            int* __restrict__ rrows, int Mpad) {
  int t = blockIdx.x * 256 + threadIdx.x;
  if (t >= Mpad) return;
  int mc = *mcount;
  rrows[t] = (t < mc) ? mlist[t] : 0;
}

// ---------------- fp32 -> bf16 convert (vectorized) ----------------
__global__ void cvt_f32_bf16(const float* __restrict__ src, u16* __restrict__ dst, int n4) {
  int t = blockIdx.x * 256 + threadIdx.x;
  if (t >= n4) return;
  float4 v = ((const float4*)src)[t];
  u16x4_t o;
  o.x = f2b(v.x); o.y = f2b(v.y); o.z = f2b(v.z); o.w = f2b(v.w);
  ((u16x4_t*)dst)[t] = o;
}

// ---------------- masked CSR build ----------------
__global__ void count_edges(const int* __restrict__ obj_idx, const int* __restrict__ mask,
                            int* __restrict__ deg, int n) {
  int e = blockIdx.x * 256 + threadIdx.x;
  if (e >= n) return;
  int o = obj_idx[e];
  if (mask[o]) atomicAdd(&deg[o], 1);
}

// exclusive scan of deg[0..n) -> offs, 3-kernel hierarchical (n<=65536 -> nb<=256)
__global__ void scan_block(const int* __restrict__ deg, int* __restrict__ offs,
                           int* __restrict__ bsum, int n) {
  __shared__ int tmp[256];
  int t = threadIdx.x;
  int i = blockIdx.x * 256 + t;
  int v = (i < n) ? deg[i] : 0;
  tmp[t] = v;
  __syncthreads();
  for (int off = 1; off < 256; off <<= 1) {
    int x = (t >= off) ? tmp[t - off] : 0;
    __syncthreads();
    tmp[t] += x;
    __syncthreads();
  }
  if (i < n) offs[i] = tmp[t] - v;
  if (t == 255) bsum[blockIdx.x] = tmp[255];
}

__global__ void scan_tops(int* __restrict__ bsum, int nb) {
  __shared__ int tmp[256];
  int t = threadIdx.x;
  int v = (t < nb) ? bsum[t] : 0;
  tmp[t] = v;
  __syncthreads();
  for (int off = 1; off < 256; off <<= 1) {
    int x = (t >= off) ? tmp[t - off] : 0;
    __syncthreads();
    tmp[t] += x;
    __syncthreads();
  }
  if (t < nb) bsum[t] = tmp[t] - v;
}

__global__ void scan_add(int* __restrict__ offs, const int* __restrict__ bsum, int n) {
  int i = blockIdx.x * 256 + threadIdx.x;
  if (i < n) offs[i] += bsum[blockIdx.x];
}

__global__ void fill_edges(const int* __restrict__ obj_idx, const int* __restrict__ evt_idx,
                           const int* __restrict__ mask, const int* __restrict__ offs,
                           int* __restrict__ cursor, int* __restrict__ elist, int n) {
  int e = blockIdx.x * 256 + threadIdx.x;
  if (e >= n) return;
  int o = obj_idx[e];
  if (!mask[o]) return;
  int pos = atomicAdd(&cursor[o], 1);
  elist[offs[o] + pos] = evt_idx[e];
}

// ---------------- register-accumulated scatter-mean, compacted output ----------------
// one wave per compact main object; lane covers dims [lane*4, lane*4+4)
__global__ __launch_bounds__(256)
void accum_prof(const u16* __restrict__ P, const int* __restrict__ elist,
                const int* __restrict__ offs, const int* __restrict__ deg,
                const int* __restrict__ mlist, const int* __restrict__ mcount,
                u16* __restrict__ prof, int Mpad) {
  const int wave = threadIdx.x >> 6;
  const int lane = threadIdx.x & 63;
  const int i = blockIdx.x * 4 + wave;
  if (i >= Mpad) return;
  const int mc = *mcount;
  float a0 = 0.f, a1 = 0.f, a2 = 0.f, a3 = 0.f;
  int d = 0;
  if (i < mc) {
    const int o = mlist[i];
    const int off = offs[o];
    d = deg[o];
    int j = 0;
    for (; j + 1 < d; j += 2) {
      int e0 = elist[off + j], e1 = elist[off + j + 1];
      u16x4_t p0 = *(const u16x4_t*)(P + (size_t)e0 * 256 + lane * 4);
      u16x4_t p1 = *(const u16x4_t*)(P + (size_t)e1 * 256 + lane * 4);
      a0 += b2f(p0.x) + b2f(p1.x);
      a1 += b2f(p0.y) + b2f(p1.y);
      a2 += b2f(p0.z) + b2f(p1.z);
      a3 += b2f(p0.w) + b2f(p1.w);
    }
    if (j < d) {
      int e0 = elist[off + j];
      u16x4_t p0 = *(const u16x4_t*)(P + (size_t)e0 * 256 + lane * 4);
      a0 += b2f(p0.x); a1 += b2f(p0.y); a2 += b2f(p0.z); a3 += b2f(p0.w);
    }
  }
  float s = 1.f / fmaxf((float)d, 1.f);
  u16x4_t ov;
  ov.x = f2b(a0 * s); ov.y = f2b(a1 * s); ov.z = f2b(a2 * s); ov.w = f2b(a3 * s);
  *(u16x4_t*)(prof + (size_t)i * 256 + lane * 4) = ov;
}

// ---------------- bf16 MFMA GEMM: C[M,N] = A[M,K] @ B[N,K]^T + bias, opt relu/gather ----------------
template<int RELU, int GATHER>
__global__ __launch_bounds__(256, 2)
void gemm_bt_bf16(const u16* __restrict__ A, const u16* __restrict__ B,
                  const float* __restrict__ bias, u16* __restrict__ C,
                  const int* __restrict__ ridx, int M, int N, int K) {
  __shared__ u16 lA[128 * 64];
  __shared__ u16 lB[128 * 64];
  const int tid  = threadIdx.x;
  const int lane = tid & 63;
  const int wave = tid >> 6;
  const int m0 = blockIdx.x * 128;
  const int n0 = blockIdx.y * 128;

  f32x4 acc[4][4] = {};

  const int mR = (wave & 1) * 64;
  const int nC = (wave >> 1) * 64;

  for (int kt = 0; kt < K; kt += 64) {
    __syncthreads();
#pragma unroll
    for (int s = 0; s < 4; ++s) {
      int slot = s * 256 + tid;
      int row  = slot >> 3;
      int kk   = (slot & 7) * 8;
      int ar;
      if (GATHER) {
        ar = ridx[m0 + row];           // grid covers exactly Mpad rows
      } else {
        ar = m0 + row; ar = (ar < M) ? ar : (M - 1);
      }
      const u16* gA = A + (size_t)ar * K + (kt + kk);
      __builtin_amdgcn_global_load_lds(
          (const __attribute__((address_space(1))) void*)gA,
          (__attribute__((address_space(3))) void*)(lA + s * 2048 + wave * 512),
          16, 0, 0);
      const u16* gB = B + (size_t)(n0 + row) * K + (kt + kk);
      __builtin_amdgcn_global_load_lds(
          (const __attribute__((address_space(1))) void*)gB,
          (__attribute__((address_space(3))) void*)(lB + s * 2048 + wave * 512),
          16, 0, 0);
    }
    __syncthreads();

#pragma unroll
    for (int ks = 0; ks < 2; ++ks) {
      const int kb = ks * 32 + (lane >> 4) * 8;
      bf16x8 af[4], bfr[4];
#pragma unroll
      for (int i = 0; i < 4; ++i) {
        af[i]  = *(const bf16x8*)(lA + (mR + i * 16 + (lane & 15)) * 64 + kb);
        bfr[i] = *(const bf16x8*)(lB + (nC + i * 16 + (lane & 15)) * 64 + kb);
      }
#pragma unroll
      for (int i = 0; i < 4; ++i)
#pragma unroll
        for (int j = 0; j < 4; ++j)
          acc[i][j] = __builtin_amdgcn_mfma_f32_16x16x32_bf16(af[i], bfr[j], acc[i][j], 0, 0, 0);
    }
  }

  const int crow = (lane >> 4) * 4;
  const int ccol = lane & 15;
#pragma unroll
  for (int i = 0; i < 4; ++i) {
#pragma unroll
    for (int j = 0; j < 4; ++j) {
      int col = n0 + nC + j * 16 + ccol;
      float bv = bias[col];
#pragma unroll
      for (int q = 0; q < 4; ++q) {
        int row = m0 + mR + i * 16 + crow + q;
        if (row < M) {
          float v = acc[i][j][q] + bv;
          if (RELU) v = fmaxf(v, 0.f);
          C[(size_t)row * N + col] = f2b(v);
        }
      }
    }
  }
}

// ---------------- GRU gates + masked blend (compact gi/gh via cpos) ----------------
__global__ __launch_bounds__(256)
void gate_out(const u16* __restrict__ gi, const u16* __restrict__ gh,
              const float* __restrict__ objX, const int* __restrict__ mask,
              const int* __restrict__ cpos, float* __restrict__ out, int nObj) {
  const int row = blockIdx.x;
  const int d = threadIdx.x;
  const size_t o256 = (size_t)row * 256 + d;
  float x = objX[o256];
  float res = x;
  if (mask[row]) {
    const size_t c768 = (size_t)cpos[row] * 768 + d;
    float ir = b2f(gi[c768]), iz = b2f(gi[c768 + 256]), inn = b2f(gi[c768 + 512]);
    float hr = b2f(gh[c768]), hz = b2f(gh[c768 + 256]), hn = b2f(gh[c768 + 512]);
    float r = 1.f / (1.f + __expf(-(ir + hr)));
    float z = 1.f / (1.f + __expf(-(iz + hz)));
    float a = inn + r * hn;
    float n = 1.f - 2.f / (__expf(2.f * a) + 1.f);
    res = (1.f - z) * n + z * x;
  }
  out[o256] = res;
}

// ---------------- workspace layout (bytes) ----------------
// 0          evtb  51,200,000   (dead after gemm1)   -> gi reuse (38,535,168)
// 51,200,000 P     51,200,000   (dead after accum)   -> gh reuse (38,535,168)
// 102,400,000 objb 25,600,000
// 128,000,000 prof 12,845,056   (25088 x 256 bf16, compact)
// 140,845,056 wpb     131,072
// 140,976,128 wib     393,216
// 141,369,344 whb     393,216
// 141,762,560 deg     200,000   \
// 141,962,560 offs    200,000    |
// 142,162,560 cursor  200,000    | zeroed by one memset
// 142,362,560 mask    200,000    | (1,201,792 B)
// 142,562,560 cpos    200,000    |
// 142,762,560 mlist   100,352    |
// 142,862,912 rrows   100,352    |
// 142,963,264 bsum      1,024    |
// 142,964,288 mcount       64   /
// 142,964,352 elist  2,000,000
// total 144,964,352

extern "C" void kernel_launch(void* const* d_in, const int* in_sizes, int n_in,
                              void* d_out, int out_size, void* d_ws, size_t ws_size,
                              hipStream_t stream) {
  const float* objX   = (const float*)d_in[0];
  const float* evtX   = (const float*)d_in[1];
  const int* obj_idx  = (const int*)d_in[2];
  const int* evt_idx  = (const int*)d_in[3];
  const int* main_idx = (const int*)d_in[4];
  const float* Wp = (const float*)d_in[5];
  const float* bp = (const float*)d_in[6];
  const float* Wi = (const float*)d_in[7];
  const float* bi = (const float*)d_in[8];
  const float* Wh = (const float*)d_in[9];
  const float* bh = (const float*)d_in[10];

  const int nObj  = in_sizes[0] / 256;   // 50000
  const int nEvt  = in_sizes[1] / 256;   // 100000
  const int nEdge = in_sizes[2];         // 500000
  const int nMain = in_sizes[4];         // 25000
  const int Mpad  = ((nMain + 127) / 128) * 128;  // 25088

  char* ws = (char*)d_ws;
  u16*   evtb  = (u16*)(ws + 0);
  u16*   P     = (u16*)(ws + 51200000);
  u16*   objb  = (u16*)(ws + 102400000);
  u16*   prof  = (u16*)(ws + 128000000);
  u16*   wpb   = (u16*)(ws + 140845056);
  u16*   wib   = (u16*)(ws + 140976128);
  u16*   whb   = (u16*)(ws + 141369344);
  int*   deg   = (int*)(ws + 141762560);
  int*   offs  = (int*)(ws + 141962560);
  int*   cursor= (int*)(ws + 142162560);
  int*   mask  = (int*)(ws + 142362560);
  int*   cpos  = (int*)(ws + 142562560);
  int*   mlist = (int*)(ws + 142762560);
  int*   rrows = (int*)(ws + 142862912);
  int*   bsum  = (int*)(ws + 142963264);
  int*   mcount= (int*)(ws + 142964288);
  int*   elist = (int*)(ws + 142964352);
  u16*   gi    = (u16*)(ws + 0);
  u16*   gh    = (u16*)(ws + 51200000);
  float* out   = (float*)d_out;

  // zero deg..mcount in one shot
  hipMemsetAsync(ws + 141762560, 0, 1201792, stream);

  set_mask_append<<<(nMain + 255) / 256, 256, 0, stream>>>(main_idx, mask, mlist, cpos, mcount, nMain);

  cvt_f32_bf16<<<(in_sizes[1] / 4 + 255) / 256, 256, 0, stream>>>(evtX, evtb, in_sizes[1] / 4);
  cvt_f32_bf16<<<(in_sizes[0] / 4 + 255) / 256, 256, 0, stream>>>(objX, objb, in_sizes[0] / 4);
  cvt_f32_bf16<<<(65536 / 4 + 255) / 256, 256, 0, stream>>>(Wp, wpb, 65536 / 4);
  cvt_f32_bf16<<<(196608 / 4 + 255) / 256, 256, 0, stream>>>(Wi, wib, 196608 / 4);
  cvt_f32_bf16<<<(196608 / 4 + 255) / 256, 256, 0, stream>>>(Wh, whb, 196608 / 4);

  // P = relu(event_bf16 @ Wp^T + bp)   [100000 x 256]
  gemm_bt_bf16<1, 0><<<dim3((nEvt + 127) / 128, 2), 256, 0, stream>>>(
      evtb, wpb, bp, P, nullptr, nEvt, 256, 256);

  // masked CSR
  count_edges<<<(nEdge + 255) / 256, 256, 0, stream>>>(obj_idx, mask, deg, nEdge);
  scan_block<<<(nObj + 255) / 256, 256, 0, stream>>>(deg, offs, bsum, nObj);
  scan_tops<<<1, 256, 0, stream>>>(bsum, (nObj + 255) / 256);
  scan_add<<<(nObj + 255) / 256, 256, 0, stream>>>(offs, bsum, nObj);
  fill_edges<<<(nEdge + 255) / 256, 256, 0, stream>>>(obj_idx, evt_idx, mask, offs, cursor, elist, nEdge);

  // register scatter-mean -> compact bf16 profile
  accum_prof<<<(Mpad + 3) / 4, 256, 0, stream>>>(P, elist, offs, deg, mlist, mcount, prof, Mpad);

  build_rrows<<<(Mpad + 255) / 256, 256, 0, stream>>>(mlist, mcount, rrows, Mpad);

  // compact GRU GEMMs [25088 x 768]
  gemm_bt_bf16<0, 0><<<dim3(Mpad / 128, 6), 256, 0, stream>>>(
      prof, wib, bi, gi, nullptr, Mpad, 768, 256);
  gemm_bt_bf16<0, 1><<<dim3(Mpad / 128, 6), 256, 0, stream>>>(
      objb, whb, bh, gh, rrows, Mpad, 768, 256);

  // gates + masked blend
  gate_out<<<nObj, 256, 0, stream>>>(gi, gh, objX, mask, cpos, out, nObj);
}